// Round 4
// baseline (831.450 us; speedup 1.0000x reference)
//
#include <hip/hip_runtime.h>
#include <math.h>

#define T_ 1024
#define D_ 3
#define H_ 64

typedef _Float16 f16x8 __attribute__((ext_vector_type(8)));
typedef float f32x4 __attribute__((ext_vector_type(4)));

__device__ __forceinline__ float sigmoid_f(float x) {
    return __builtin_amdgcn_rcpf(1.0f + __expf(-x));
}

#define MFMA(A, B, C) __builtin_amdgcn_mfma_f32_16x16x32_f16((A), (B), (C), 0, 0, 0)

// 8 waves/block, one 16-row group (8 seqs x 2 Siamese chains) per block.
// Wave pair (w, w+4): both own hidden units [16w,16w+16) and run the full
// 9-MFMA gate matmul (duplicated - MFMA is ~10% of issue), but wave w does
// gate math + h-publish for C-rows {4q+0,4q+1} and wave w+4 for {4q+2,4q+3}.
// -> trans work per wave halves, wave count doubles (4/SIMD latency hiding).
// Single barrier per step (double-buffered h tile). Sigmoid pair r,z share
// one v_rcp. x loads batched float4x3 per 4 steps, 8-step prefetch distance.
__global__ __launch_bounds__(512, 4) void gru_mfma8(
    const float* __restrict__ x1, const float* __restrict__ x2,
    const float* __restrict__ W_ih, const float* __restrict__ W_hh,
    const float* __restrict__ b_ih, const float* __restrict__ b_hh,
    const float* __restrict__ W1, const float* __restrict__ b1,
    const float* __restrict__ W2, const float* __restrict__ b2,
    float* __restrict__ out)
{
    const int lane = threadIdx.x & 63;
    const int w4   = threadIdx.x >> 6;     // 0..7
    const int w    = w4 & 3;               // unit group: units 16w..16w+15
    const int rsel = (w4 >> 2) * 2;        // gate rows handled: rsel, rsel+1
    const int c    = lane & 15;            // A-m / C-D col / B-n
    const int q    = lane >> 4;            // quad
    const int u    = 16 * w + c;           // this lane's hidden-unit column
    const int seq0 = blockIdx.x * 8;

    // ---- h-part B-fragments: wf[g][ks][j] = W_hh[g*64+u][32*ks+q*8+j] ----
    f16x8 wf[3][2];
    #pragma unroll
    for (int g = 0; g < 3; ++g)
        #pragma unroll
        for (int ks = 0; ks < 2; ++ks) {
            const float* p = W_hh + (size_t)(g * 64 + u) * H_ + 32 * ks + q * 8;
            f16x8 v;
            #pragma unroll
            for (int j = 0; j < 8; ++j) v[j] = (_Float16)p[j];
            wf[g][ks] = v;
        }

    // ---- x-part B-fragments (k=0..2 live in q==0 lanes only) ----
    f16x8 bxf[3];
    #pragma unroll
    for (int g = 0; g < 3; ++g) {
        f16x8 v = {};
        if (q == 0) {
            #pragma unroll
            for (int d = 0; d < 3; ++d)
                v[d] = (_Float16)W_ih[(size_t)(g * 64 + u) * D_ + d];
        }
        bxf[g] = v;
    }

    // ---- bias C-splats ----
    const float comb_r = b_ih[u]        + b_hh[u];
    const float comb_z = b_ih[64 + u]   + b_hh[64 + u];
    const float bxn    = b_ih[128 + u];
    const float bhn    = b_hh[128 + u];
    const f32x4 Cr  = {comb_r, comb_r, comb_r, comb_r};
    const f32x4 Cz  = {comb_z, comb_z, comb_z, comb_z};
    const f32x4 Cxn = {bxn, bxn, bxn, bxn};
    const f32x4 Chn = {bhn, bhn, bhn, bhn};

    // ---- x pointer for A-frag row c (rows 0..7 = chain1, 8..15 = chain2) ----
    const float* xptr = (c < 8) ? (x1 + (size_t)(seq0 + c) * (T_ * D_))
                                : (x2 + (size_t)(seq0 + c - 8) * (T_ * D_));

    // h-tile double buffer: [row][unit], stride 72 halves
    __shared__ alignas(16) _Float16 hb[2][16 * 72];
    __shared__ float dlds[8][68];

    float h[2];                       // rows 4q+rsel, 4q+rsel+1, col u
    h[0] = 0.f; h[1] = 0.f;

    auto step = [&](int buf, float x0, float x1v, float x2v) {
        // x k-extension A-fragment (q==0 lanes carry x at k=0..2)
        f16x8 ax = {};
        if (q == 0) {
            ax[0] = (_Float16)x0; ax[1] = (_Float16)x1v; ax[2] = (_Float16)x2v;
        }
        // publish this wave's h rows (f16) to this step's buffer
        hb[buf][(4 * q + rsel + 0) * 72 + u] = (_Float16)h[0];
        hb[buf][(4 * q + rsel + 1) * 72 + u] = (_Float16)h[1];
        __syncthreads();
        const f16x8 a0 = *(const f16x8*)&hb[buf][c * 72 + q * 8];        // k 0..31
        const f16x8 a1 = *(const f16x8*)&hb[buf][c * 72 + 32 + q * 8];   // k 32..63

        f32x4 ar  = MFMA(ax, bxf[0], Cr);
        f32x4 az  = MFMA(ax, bxf[1], Cz);
        f32x4 axn = MFMA(ax, bxf[2], Cxn);
        f32x4 ahn = MFMA(a0, wf[2][0], Chn);
        ar  = MFMA(a0, wf[0][0], ar);
        az  = MFMA(a0, wf[1][0], az);
        ahn = MFMA(a1, wf[2][1], ahn);
        ar  = MFMA(a1, wf[0][1], ar);
        az  = MFMA(a1, wf[1][1], az);

        // gates for this wave's 2 rows; sigmoid pair shares one rcp
        #pragma unroll
        for (int i = 0; i < 2; ++i) {
            const int r = rsel + i;
            const float eu = __expf(-ar[r]);
            const float ev = __expf(-az[r]);
            const float pu = 1.0f + eu, pv = 1.0f + ev;
            const float inv = __builtin_amdgcn_rcpf(pu * pv);
            const float rr = pv * inv;          // sigmoid(ar)
            const float zz = pu * inv;          // sigmoid(az)
            const float tt = axn[r] + rr * ahn[r];
            const float e2 = __expf(2.0f * tt);
            const float nn = 1.0f - 2.0f * __builtin_amdgcn_rcpf(e2 + 1.0f);
            h[i] = nn + zz * (h[i] - nn);
        }
    };

    // x batched: float4 x3 = 12 floats = 4 steps; two buffers = 8 steps/iter
    const float4* xp4 = (const float4*)xptr;
    float4 xA[3], xB[3];
    #pragma unroll
    for (int i = 0; i < 3; ++i) { xA[i] = xp4[i]; xB[i] = xp4[3 + i]; }

    for (int t = 0; t < T_; t += 8) {
        float4 nA[3], nB[3];
        const int ta = (t + 8 < T_) ? (t + 8) : t;    // clamp: values unused at tail
        const int tb = (t + 12 < T_) ? (t + 12) : t;
        #pragma unroll
        for (int i = 0; i < 3; ++i) nA[i] = xp4[(ta * 3) / 4 + i];
        step(0, xA[0].x, xA[0].y, xA[0].z);
        step(1, xA[0].w, xA[1].x, xA[1].y);
        step(0, xA[1].z, xA[1].w, xA[2].x);
        step(1, xA[2].y, xA[2].z, xA[2].w);
        #pragma unroll
        for (int i = 0; i < 3; ++i) nB[i] = xp4[(tb * 3) / 4 + i];
        step(0, xB[0].x, xB[0].y, xB[0].z);
        step(1, xB[0].w, xB[1].x, xB[1].y);
        step(0, xB[1].z, xB[1].w, xB[2].x);
        step(1, xB[2].y, xB[2].z, xB[2].w);
        #pragma unroll
        for (int i = 0; i < 3; ++i) { xA[i] = nA[i]; xB[i] = nB[i]; }
    }

    // ---- epilogue: |h1-h2| -> Linear(64,32)+ReLU -> Linear(32,1)+sigmoid ----
    #pragma unroll
    for (int i = 0; i < 2; ++i) {
        const float o = __shfl_xor(h[i], 32);     // row m <-> m^8 (q ^= 2)
        if (q < 2) dlds[4 * q + rsel + i][u] = fabsf(h[i] - o);
    }
    __syncthreads();
    if (w4 == 0) {
        const int s = lane >> 3;   // seq within block 0..7
        const int b = lane & 7;    // hidden-row group base
        float am[4];
        #pragma unroll
        for (int i = 0; i < 4; ++i) am[i] = b1[b + 8 * i];
        #pragma unroll
        for (int k4 = 0; k4 < 16; ++k4) {
            const float4 dvec = *(const float4*)&dlds[s][k4 * 4];
            #pragma unroll
            for (int i = 0; i < 4; ++i) {
                const float4 wv = *(const float4*)&W1[(b + 8 * i) * H_ + k4 * 4];
                am[i] += dvec.x * wv.x + dvec.y * wv.y + dvec.z * wv.z + dvec.w * wv.w;
            }
        }
        float part = 0.f;
        #pragma unroll
        for (int i = 0; i < 4; ++i) part += fmaxf(am[i], 0.f) * W2[b + 8 * i];
        part += __shfl_xor(part, 1);
        part += __shfl_xor(part, 2);
        part += __shfl_xor(part, 4);
        if (b == 0) out[seq0 + s] = sigmoid_f(part + b2[0]);
    }
}

extern "C" void kernel_launch(void* const* d_in, const int* in_sizes, int n_in,
                              void* d_out, int out_size, void* d_ws, size_t ws_size,
                              hipStream_t stream) {
    const float* x1   = (const float*)d_in[0];
    const float* x2   = (const float*)d_in[1];
    const float* W_ih = (const float*)d_in[2];
    const float* W_hh = (const float*)d_in[3];
    const float* b_ih = (const float*)d_in[4];
    const float* b_hh = (const float*)d_in[5];
    const float* W1   = (const float*)d_in[6];
    const float* b1   = (const float*)d_in[7];
    const float* W2   = (const float*)d_in[8];
    const float* b2   = (const float*)d_in[9];

    const int B = in_sizes[0] / (T_ * D_);      // 4096
    dim3 grid(B / 8), block(512);
    gru_mfma8<<<grid, block, 0, stream>>>(x1, x2, W_ih, W_hh, b_ih, b_hh,
                                          W1, b1, W2, b2, (float*)d_out);
}

// Round 5
// 578.313 us; speedup vs baseline: 1.4377x; 1.4377x over previous
//
#include <hip/hip_runtime.h>
#include <math.h>

#define T_ 1024
#define D_ 3
#define H_ 64

typedef _Float16 f16x8 __attribute__((ext_vector_type(8)));
typedef float f32x4 __attribute__((ext_vector_type(4)));

__device__ __forceinline__ float sigmoid_f(float x) {
    return __builtin_amdgcn_rcpf(1.0f + __expf(-x));
}

#define MFMA(A, B, C) __builtin_amdgcn_mfma_f32_16x16x32_f16((A), (B), (C), 0, 0, 0)

// Round-3 structure (best: 672 us) + issue-count diet.
// 4 waves/block cooperate on one 16-row group (8 seqs x 2 Siamese chains).
// Wave w owns hidden units [16w,16w+16): r,z,n gates for its units.
// Per step: publish h -> x-MFMAs (h-independent, pre-barrier) -> barrier ->
// 6 h-MFMAs -> gate math (exp2-folded weights: r,z rows scaled by -log2e,
// n rows by 2*log2e -> bare v_exp_f32; sigmoid pair shares one v_rcp).
__global__ __launch_bounds__(256, 2) void gru_mfma5(
    const float* __restrict__ x1, const float* __restrict__ x2,
    const float* __restrict__ W_ih, const float* __restrict__ W_hh,
    const float* __restrict__ b_ih, const float* __restrict__ b_hh,
    const float* __restrict__ W1, const float* __restrict__ b1,
    const float* __restrict__ W2, const float* __restrict__ b2,
    float* __restrict__ out)
{
    const int lane = threadIdx.x & 63;
    const int w    = threadIdx.x >> 6;   // wave 0..3: owns units 16w..16w+15
    const int c    = lane & 15;          // A-m / C-D col / B-n
    const int q    = lane >> 4;          // quad
    const int u    = 16 * w + c;         // this lane's hidden-unit column
    const int seq0 = blockIdx.x * 8;

    const float SRZ = -1.44269504f;      // -log2(e): r,z rows (exp2(-x) form)
    const float SN  =  2.88539008f;      // 2*log2(e): n rows (exp2(2x) form)
    const float gsc[3] = {SRZ, SRZ, SN};

    // ---- h-part B-fragments (scaled): wf[g][ks][j] = s_g*W_hh[g*64+u][32ks+8q+j]
    f16x8 wf[3][2];
    #pragma unroll
    for (int g = 0; g < 3; ++g)
        #pragma unroll
        for (int ks = 0; ks < 2; ++ks) {
            const float* p = W_hh + (size_t)(g * 64 + u) * H_ + 32 * ks + q * 8;
            f16x8 v;
            #pragma unroll
            for (int j = 0; j < 8; ++j) v[j] = (_Float16)(p[j] * gsc[g]);
            wf[g][ks] = v;
        }

    // ---- x-part B-fragments (scaled; nonzero only in q==0 lanes, j<3) ----
    f16x8 bxf[3];
    #pragma unroll
    for (int g = 0; g < 3; ++g) {
        f16x8 v = {};
        if (q == 0) {
            #pragma unroll
            for (int d = 0; d < 3; ++d)
                v[d] = (_Float16)(W_ih[(size_t)(g * 64 + u) * D_ + d] * gsc[g]);
        }
        bxf[g] = v;
    }

    // ---- bias C-splats (scaled) ----
    const float comb_r = (b_ih[u]      + b_hh[u])      * SRZ;
    const float comb_z = (b_ih[64 + u] + b_hh[64 + u]) * SRZ;
    const float bxn    = b_ih[128 + u] * SN;
    const float bhn    = b_hh[128 + u] * SN;
    const f32x4 Cr  = {comb_r, comb_r, comb_r, comb_r};
    const f32x4 Cz  = {comb_z, comb_z, comb_z, comb_z};
    const f32x4 Cxn = {bxn, bxn, bxn, bxn};
    const f32x4 Chn = {bhn, bhn, bhn, bhn};

    // ---- x pointer for A-frag row c (rows 0..7 = chain1, 8..15 = chain2) ----
    const float* xptr = (c < 8) ? (x1 + (size_t)(seq0 + c) * (T_ * D_))
                                : (x2 + (size_t)(seq0 + c - 8) * (T_ * D_));

    // h-tile double buffer: [row][unit], stride 72 halves
    __shared__ alignas(16) _Float16 hb[2][16 * 72];
    __shared__ float dlds[8][68];

    float h[4];                          // rows 4q+0..3, col u
    #pragma unroll
    for (int r = 0; r < 4; ++r) h[r] = 0.f;

    auto step = [&](int buf, float x0, float x1v, float x2v) {
        // publish h(t) first — other waves' barrier wait ends sooner
        #pragma unroll
        for (int r = 0; r < 4; ++r)
            hb[buf][(4 * q + r) * 72 + u] = (_Float16)h[r];
        // x-part MFMAs: independent of h(t), fill the pre-barrier gap.
        // No lane masking needed: bxf is zero wherever ax is junk.
        f16x8 ax = {};
        ax[0] = (_Float16)x0; ax[1] = (_Float16)x1v; ax[2] = (_Float16)x2v;
        f32x4 ar  = MFMA(ax, bxf[0], Cr);
        f32x4 az  = MFMA(ax, bxf[1], Cz);
        f32x4 axn = MFMA(ax, bxf[2], Cxn);
        __syncthreads();
        const f16x8 a0 = *(const f16x8*)&hb[buf][c * 72 + q * 8];        // k 0..31
        const f16x8 a1 = *(const f16x8*)&hb[buf][c * 72 + 32 + q * 8];   // k 32..63

        ar  = MFMA(a0, wf[0][0], ar);
        az  = MFMA(a0, wf[1][0], az);
        f32x4 ahn = MFMA(a0, wf[2][0], Chn);
        ar  = MFMA(a1, wf[0][1], ar);
        az  = MFMA(a1, wf[1][1], az);
        ahn = MFMA(a1, wf[2][1], ahn);

        // gates: ar,az hold -log2e*preact; axn,ahn hold 2log2e*parts
        #pragma unroll
        for (int r = 0; r < 4; ++r) {
            const float eu = __builtin_amdgcn_exp2f(ar[r]);   // e^{-pre_r}
            const float ev = __builtin_amdgcn_exp2f(az[r]);   // e^{-pre_z}
            const float pu = 1.0f + eu, pv = 1.0f + ev;
            const float inv = __builtin_amdgcn_rcpf(pu * pv);
            const float rr = pv * inv;                        // sigmoid(pre_r)
            const float zz = pu * inv;                        // sigmoid(pre_z)
            const float tt = axn[r] + rr * ahn[r];            // 2log2e * pre_n
            const float e2 = __builtin_amdgcn_exp2f(tt);      // e^{2 pre_n}
            const float nn = 1.0f - 2.0f * __builtin_amdgcn_rcpf(e2 + 1.0f);
            h[r] = nn + zz * (h[r] - nn);
        }
    };

    // x batched: float4 x3 = 12 floats = 4 steps; prefetch distance 4 steps
    const float4* xp4 = (const float4*)xptr;
    float4 xc[3];
    #pragma unroll
    for (int i = 0; i < 3; ++i) xc[i] = xp4[i];

    for (int t = 0; t < T_; t += 4) {
        float4 xn[3];
        const int tb = (t + 4 < T_) ? (3 * (t + 4)) / 4 : (3 * t) / 4;
        #pragma unroll
        for (int i = 0; i < 3; ++i) xn[i] = xp4[tb + i];
        step(0, xc[0].x, xc[0].y, xc[0].z);
        step(1, xc[0].w, xc[1].x, xc[1].y);
        step(0, xc[1].z, xc[1].w, xc[2].x);
        step(1, xc[2].y, xc[2].z, xc[2].w);
        #pragma unroll
        for (int i = 0; i < 3; ++i) xc[i] = xn[i];
    }

    // ---- epilogue: |h1-h2| -> Linear(64,32)+ReLU -> Linear(32,1)+sigmoid ----
    #pragma unroll
    for (int r = 0; r < 4; ++r) {
        const float o = __shfl_xor(h[r], 32);     // row m <-> m^8 (q ^= 2)
        if (q < 2) dlds[4 * q + r][u] = fabsf(h[r] - o);
    }
    __syncthreads();
    if (w == 0) {
        const int s = lane >> 3;   // seq within block 0..7
        const int b = lane & 7;    // hidden-row group base
        float am[4];
        #pragma unroll
        for (int i = 0; i < 4; ++i) am[i] = b1[b + 8 * i];
        #pragma unroll
        for (int k4 = 0; k4 < 16; ++k4) {
            const float4 dvec = *(const float4*)&dlds[s][k4 * 4];
            #pragma unroll
            for (int i = 0; i < 4; ++i) {
                const float4 wv = *(const float4*)&W1[(b + 8 * i) * H_ + k4 * 4];
                am[i] += dvec.x * wv.x + dvec.y * wv.y + dvec.z * wv.z + dvec.w * wv.w;
            }
        }
        float part = 0.f;
        #pragma unroll
        for (int i = 0; i < 4; ++i) part += fmaxf(am[i], 0.f) * W2[b + 8 * i];
        part += __shfl_xor(part, 1);
        part += __shfl_xor(part, 2);
        part += __shfl_xor(part, 4);
        if (b == 0) out[seq0 + s] = sigmoid_f(part + b2[0]);
    }
}

extern "C" void kernel_launch(void* const* d_in, const int* in_sizes, int n_in,
                              void* d_out, int out_size, void* d_ws, size_t ws_size,
                              hipStream_t stream) {
    const float* x1   = (const float*)d_in[0];
    const float* x2   = (const float*)d_in[1];
    const float* W_ih = (const float*)d_in[2];
    const float* W_hh = (const float*)d_in[3];
    const float* b_ih = (const float*)d_in[4];
    const float* b_hh = (const float*)d_in[5];
    const float* W1   = (const float*)d_in[6];
    const float* b1   = (const float*)d_in[7];
    const float* W2   = (const float*)d_in[8];
    const float* b2   = (const float*)d_in[9];

    const int B = in_sizes[0] / (T_ * D_);      // 4096
    dim3 grid(B / 8), block(256);
    gru_mfma5<<<grid, block, 0, stream>>>(x1, x2, W_ih, W_hh, b_ih, b_hh,
                                          W1, b1, W2, b2, (float*)d_out);
}